// Round 4
// baseline (122.654 us; speedup 1.0000x reference)
//
#include <hip/hip_runtime.h>

// Voxel merge (2x2x2, blocks i*4+j*2+k) + mask + LayerNorm(768) + GEMM [65536,768]x[768,192] (bf16 MFMA).
// v4: 2-deep register-staged software pipeline. Tile t+1's x-loads are issued into a second
// register set before computing tile t -> HBM latency hidden under compute, vmcnt never drains
// in the loop. Stats from registers (no raw-LDS). LDS = 24KB bf16 A-tile only, 2 barriers/tile.
#define NOUT 192
#define M_TOTAL 65536
#define OUT0 (M_TOTAL * NOUT)

typedef __attribute__((ext_vector_type(8))) short  short8;
typedef __attribute__((ext_vector_type(4))) float  f32x4;
typedef __attribute__((ext_vector_type(4))) unsigned short us4;

__device__ __forceinline__ unsigned short f2bf(float f) {
    union { float f; unsigned u; } a; a.f = f;
    unsigned r = a.u + 0x7FFFu + ((a.u >> 16) & 1u);  // RNE
    return (unsigned short)(r >> 16);
}

// Pre-pack W [768][192] fp32 -> bf16 in per-lane MFMA B-fragment order:
// Wb[((ks*12 + fn)*64 + l)*8 + e] = bf16(W[(ks*32 + (l>>4)*8 + e)*192 + fn*16 + (l&15)])
__global__ __launch_bounds__(256) void prepw_kernel(const float* __restrict__ Wm,
                                                    unsigned short* __restrict__ Wb) {
    int t = blockIdx.x * 256 + threadIdx.x;
    if (t >= 24 * 12 * 512) return;
    int e  = t & 7;
    int l  = (t >> 3) & 63;
    int f  = t >> 9;
    int fn = f % 12;
    int ks = f / 12;
    Wb[t] = f2bf(Wm[(ks * 32 + ((l >> 4) << 3) + e) * NOUT + fn * 16 + (l & 15)]);
}

struct TileData {
    float4 vs[4][3];   // 4 rows x 3 chunks of 4 merged channels (this lane's slice)
    float  mval;       // lanes 0..31: mask of (row l>>3, sub-voxel l&7)
};

__device__ __forceinline__ void load_tile(int tile, const float* __restrict__ x,
                                          const float* __restrict__ mask,
                                          int wv, int l,
                                          const int* ch_, const int* vo_, TileData& td)
{
    const int rowbase = tile << 4;
#pragma unroll
    for (int rr = 0; rr < 4; ++rr) {
        const int rg = rowbase + (wv << 2) + rr;
        const int w2 = rg & 31, h2 = (rg >> 5) & 31, d2 = (rg >> 10) & 31, b = rg >> 15;
        const int vbase = ((b * 64 + d2 * 2) * 64 + h2 * 2) * 64 + w2 * 2;
#pragma unroll
        for (int m = 0; m < 3; ++m)
            td.vs[rr][m] = *(const float4*)(x + (size_t)(vbase + vo_[m]) * 96 + ch_[m]);
    }
    if (l < 32) {
        const int rg = rowbase + (wv << 2) + (l >> 3);
        const int w2 = rg & 31, h2 = (rg >> 5) & 31, d2 = (rg >> 10) & 31, b = rg >> 15;
        const int vbase = ((b * 64 + d2 * 2) * 64 + h2 * 2) * 64 + w2 * 2;
        const int bi = l & 7;
        td.mval = mask[vbase + ((bi >> 2) << 12) + (((bi >> 1) & 1) << 6) + (bi & 1)];
    } else {
        td.mval = 0.f;
    }
}

__device__ __forceinline__ void compute_tile(int tile, TileData& td,
                                             unsigned short* Alds, const short8* __restrict__ Wv,
                                             const float4* g_, const float4* be_,
                                             const int* bi_, int wv, int l,
                                             float* __restrict__ out)
{
    const int rowbase = tile << 4;

    // ---- mask_out: OR-reduce mask over each row's 8 sub-voxels (lanes 0..31) ----
    float mo = td.mval;
    mo = fmaxf(mo, __shfl_xor(mo, 1));
    mo = fmaxf(mo, __shfl_xor(mo, 2));
    mo = fmaxf(mo, __shfl_xor(mo, 4));
    if (l < 32 && (l & 7) == 0)
        out[OUT0 + rowbase + (wv << 2) + (l >> 3)] = (mo > 0.f) ? 1.f : 0.f;

    // ---- mask-apply + per-row sums (from registers; 8 interleaved butterfly chains) ----
    float s[4], s2[4];
#pragma unroll
    for (int rr = 0; rr < 4; ++rr) {
        float a = 0.f, b2 = 0.f;
#pragma unroll
        for (int m = 0; m < 3; ++m) {
            const float mk = __shfl(td.mval, (rr << 3) + bi_[m]);   // bpermute broadcast
            float4 v = td.vs[rr][m];
            v.x *= mk; v.y *= mk; v.z *= mk; v.w *= mk;
            td.vs[rr][m] = v;
            a  += (v.x + v.y) + (v.z + v.w);
            b2 += (v.x * v.x + v.y * v.y) + (v.z * v.z + v.w * v.w);
        }
        s[rr] = a; s2[rr] = b2;
    }
#pragma unroll
    for (int off = 32; off >= 1; off >>= 1) {
#pragma unroll
        for (int rr = 0; rr < 4; ++rr) {
            s[rr]  += __shfl_xor(s[rr],  off);
            s2[rr] += __shfl_xor(s2[rr], off);
        }
    }

    // ---- normalize -> bf16 A-tile in LDS (row-private writes, XOR-swizzled) ----
#pragma unroll
    for (int rr = 0; rr < 4; ++rr) {
        const int r = (wv << 2) + rr;
        const float mu  = s[rr] * (1.f / 768.f);
        const float var = s2[rr] * (1.f / 768.f) - mu * mu;
        const float rs  = rsqrtf(var + 1e-5f);
        char* abase = (char*)Alds + r * 1536;
        const int swz = (r & 7) << 4;
#pragma unroll
        for (int m = 0; m < 3; ++m) {
            const float4 v = td.vs[rr][m];
            us4 o;
            o.x = f2bf((v.x - mu) * rs * g_[m].x + be_[m].x);
            o.y = f2bf((v.y - mu) * rs * g_[m].y + be_[m].y);
            o.z = f2bf((v.z - mu) * rs * g_[m].z + be_[m].z);
            o.w = f2bf((v.w - mu) * rs * g_[m].w + be_[m].w);
            *(us4*)(abase + (((m << 9) + (l << 3)) ^ swz)) = o;
        }
    }
    __syncthreads();   // A-tile ready

    // ---- MFMA: [16 x 192] = A[16x768] * W[768x192]; wave owns 3 col-fragments ----
    f32x4 acc[3] = {};
    const int lrow = l & 15;
    const int kq   = (l >> 4) << 4;
    const int aswz = (lrow & 7) << 4;
    const char* aBase = (const char*)Alds + lrow * 1536;
    const int bbase = wv * 192 + l;
#pragma unroll 6
    for (int ks = 0; ks < 24; ++ks) {
        const short8 a  = *(const short8*)(aBase + (((ks << 6) + kq) ^ aswz));
        const short8 b0 = Wv[ks * 768 + bbase];
        const short8 b1 = Wv[ks * 768 + bbase + 64];
        const short8 b2 = Wv[ks * 768 + bbase + 128];
        acc[0] = __builtin_amdgcn_mfma_f32_16x16x32_bf16(a, b0, acc[0], 0, 0, 0);
        acc[1] = __builtin_amdgcn_mfma_f32_16x16x32_bf16(a, b1, acc[1], 0, 0, 0);
        acc[2] = __builtin_amdgcn_mfma_f32_16x16x32_bf16(a, b2, acc[2], 0, 0, 0);
    }

    // ---- direct C store (col = lane&15, row = (l>>4)*4+j); 16-lane groups -> 64B segments ----
    const int colb = wv * 48 + lrow;
    const int r0   = rowbase + ((l >> 4) << 2);
#pragma unroll
    for (int c = 0; c < 3; ++c)
#pragma unroll
        for (int j = 0; j < 4; ++j)
            out[(size_t)(r0 + j) * NOUT + colb + c * 16] = acc[c][j];
    __syncthreads();   // A-tile consumed; next tile may overwrite
}

__global__ __launch_bounds__(256, 3) void fused_kernel(
    const float* __restrict__ x, const float* __restrict__ mask,
    const float* __restrict__ gamma, const float* __restrict__ beta,
    const unsigned short* __restrict__ Wb, float* __restrict__ out)
{
    __shared__ __align__(16) unsigned short Alds[16 * 768];   // 24 KiB

    const int tid = threadIdx.x;
    const int l   = tid & 63;
    const int wv  = tid >> 6;

    int bi_[3], ch_[3], vo_[3];
#pragma unroll
    for (int m = 0; m < 3; ++m) {
        const int c8 = (m << 8) + (l << 2);
        const int bi = c8 / 96;
        bi_[m] = bi;
        ch_[m] = c8 - bi * 96;
        vo_[m] = ((bi >> 2) << 12) + (((bi >> 1) & 1) << 6) + (bi & 1);
    }
    float4 g_[3], be_[3];
#pragma unroll
    for (int m = 0; m < 3; ++m) {
        const int c8 = (m << 8) + (l << 2);
        g_[m]  = *(const float4*)(gamma + c8);
        be_[m] = *(const float4*)(beta  + c8);
    }
    const short8* Wv = (const short8*)Wb;

    // 4 tiles per block, 2-deep register rotation: loads for t+1 in flight across compute(t).
    const int t0 = blockIdx.x << 2;
    TileData tA, tB;
    load_tile(t0 + 0, x, mask, wv, l, ch_, vo_, tA);
    load_tile(t0 + 1, x, mask, wv, l, ch_, vo_, tB);
    compute_tile(t0 + 0, tA, Alds, Wv, g_, be_, bi_, wv, l, out);
    load_tile(t0 + 2, x, mask, wv, l, ch_, vo_, tA);
    compute_tile(t0 + 1, tB, Alds, Wv, g_, be_, bi_, wv, l, out);
    load_tile(t0 + 3, x, mask, wv, l, ch_, vo_, tB);
    compute_tile(t0 + 2, tA, Alds, Wv, g_, be_, bi_, wv, l, out);
    compute_tile(t0 + 3, tB, Alds, Wv, g_, be_, bi_, wv, l, out);
}

extern "C" void kernel_launch(void* const* d_in, const int* in_sizes, int n_in,
                              void* d_out, int out_size, void* d_ws, size_t ws_size,
                              hipStream_t stream) {
    const float* x     = (const float*)d_in[0];
    const float* mask  = (const float*)d_in[1];
    const float* gamma = (const float*)d_in[2];
    const float* beta  = (const float*)d_in[3];
    const float* Wm    = (const float*)d_in[4];
    float* out = (float*)d_out;
    unsigned short* Wb = (unsigned short*)d_ws;   // 294912 B scratch

    prepw_kernel<<<576, 256, 0, stream>>>(Wm, Wb);
    fused_kernel<<<1024, 256, 0, stream>>>(x, mask, gamma, beta, Wb, out);
}

// Round 5
// 101.481 us; speedup vs baseline: 1.2086x; 1.2086x over previous
//
#include <hip/hip_runtime.h>

// Voxel merge (2x2x2, blocks i*4+j*2+k) + mask + LayerNorm(768) + GEMM [65536,768]x[768,192].
// v5: SPLIT structure for ablation + throughput.
//   K1 ln_pack: gather+mask+LN -> packed bf16 A (MFMA fragment order) in ws. Pure streaming,
//               24KB LDS, ~6 blocks/CU -> block-level TLP hides gather latency.
//   K2 gemm:    no-LDS no-barrier MFMA GEMM; A-fragments read as contiguous 1KB wave-loads,
//               B (prepacked Wb) from L2, reused across 4 row-tiles per wave.
#define NOUT 192
#define M_TOTAL 65536
#define OUT0 (M_TOTAL * NOUT)

typedef __attribute__((ext_vector_type(8))) short  short8;
typedef __attribute__((ext_vector_type(4))) float  f32x4;
typedef __attribute__((ext_vector_type(4))) unsigned short us4;

__device__ __forceinline__ unsigned short f2bf(float f) {
    union { float f; unsigned u; } a; a.f = f;
    unsigned r = a.u + 0x7FFFu + ((a.u >> 16) & 1u);  // RNE
    return (unsigned short)(r >> 16);
}

// Pre-pack W [768][192] fp32 -> bf16 in per-lane MFMA B-fragment order:
// Wb[((ks*12 + fn)*64 + l)*8 + e] = bf16(W[(ks*32 + (l>>4)*8 + e)*192 + fn*16 + (l&15)])
__global__ __launch_bounds__(256) void prepw_kernel(const float* __restrict__ Wm,
                                                    unsigned short* __restrict__ Wb) {
    int t = blockIdx.x * 256 + threadIdx.x;
    if (t >= 24 * 12 * 512) return;
    int e  = t & 7;
    int l  = (t >> 3) & 63;
    int f  = t >> 9;
    int fn = f % 12;
    int ks = f / 12;
    Wb[t] = f2bf(Wm[(ks * 32 + ((l >> 4) << 3) + e) * NOUT + fn * 16 + (l & 15)]);
}

// ---------------- K1: merge + mask + LayerNorm -> packed bf16 A ----------------
// packed[((T*24 + ks)*64 + l)*8 + e] = bf16A[T*16 + (l&15)][ks*32 + (l>>4)*8 + e]
__global__ __launch_bounds__(256) void ln_pack_kernel(
    const float* __restrict__ x, const float* __restrict__ mask,
    const float* __restrict__ gamma, const float* __restrict__ beta,
    unsigned short* __restrict__ packed, float* __restrict__ out)
{
    __shared__ __align__(16) unsigned short Alds[16 * 768];   // 24 KiB
    const int tid = threadIdx.x, l = tid & 63, wv = tid >> 6;
    const int T = blockIdx.x, rowbase = T << 4;

    int bi_[3], ch_[3], vo_[3];
    float4 g_[3], be_[3];
#pragma unroll
    for (int m = 0; m < 3; ++m) {
        const int c8 = (m << 8) + (l << 2);
        const int bi = c8 / 96;
        bi_[m] = bi; ch_[m] = c8 - bi * 96;
        vo_[m] = ((bi >> 2) << 12) + (((bi >> 1) & 1) << 6) + (bi & 1);
        g_[m]  = *(const float4*)(gamma + c8);
        be_[m] = *(const float4*)(beta  + c8);
    }

    // gather this wave's 4 rows (3 float4/lane/row) + masks (lanes 0..31)
    float4 vs[4][3];
    float mval = 0.f;
#pragma unroll
    for (int rr = 0; rr < 4; ++rr) {
        const int rg = rowbase + (wv << 2) + rr;
        const int w2 = rg & 31, h2 = (rg >> 5) & 31, d2 = (rg >> 10) & 31, b = rg >> 15;
        const int vbase = ((b * 64 + d2 * 2) * 64 + h2 * 2) * 64 + w2 * 2;
#pragma unroll
        for (int m = 0; m < 3; ++m)
            vs[rr][m] = *(const float4*)(x + (size_t)(vbase + vo_[m]) * 96 + ch_[m]);
    }
    if (l < 32) {
        const int rg = rowbase + (wv << 2) + (l >> 3);
        const int w2 = rg & 31, h2 = (rg >> 5) & 31, d2 = (rg >> 10) & 31, b = rg >> 15;
        const int vbase = ((b * 64 + d2 * 2) * 64 + h2 * 2) * 64 + w2 * 2;
        const int bi = l & 7;
        mval = mask[vbase + ((bi >> 2) << 12) + (((bi >> 1) & 1) << 6) + (bi & 1)];
    }

    // mask_out: OR over each row's 8 sub-voxels
    float mo = mval;
    mo = fmaxf(mo, __shfl_xor(mo, 1));
    mo = fmaxf(mo, __shfl_xor(mo, 2));
    mo = fmaxf(mo, __shfl_xor(mo, 4));
    if (l < 32 && (l & 7) == 0)
        out[OUT0 + rowbase + (wv << 2) + (l >> 3)] = (mo > 0.f) ? 1.f : 0.f;

    // mask-apply + row sums (8 interleaved butterfly chains)
    float s[4], s2[4];
#pragma unroll
    for (int rr = 0; rr < 4; ++rr) {
        float a = 0.f, b2 = 0.f;
#pragma unroll
        for (int m = 0; m < 3; ++m) {
            const float mk = __shfl(mval, (rr << 3) + bi_[m]);
            float4 v = vs[rr][m];
            v.x *= mk; v.y *= mk; v.z *= mk; v.w *= mk;
            vs[rr][m] = v;
            a  += (v.x + v.y) + (v.z + v.w);
            b2 += (v.x * v.x + v.y * v.y) + (v.z * v.z + v.w * v.w);
        }
        s[rr] = a; s2[rr] = b2;
    }
#pragma unroll
    for (int off = 32; off >= 1; off >>= 1)
#pragma unroll
        for (int rr = 0; rr < 4; ++rr) {
            s[rr]  += __shfl_xor(s[rr],  off);
            s2[rr] += __shfl_xor(s2[rr], off);
        }

    // normalize -> swizzled LDS tile
#pragma unroll
    for (int rr = 0; rr < 4; ++rr) {
        const int r = (wv << 2) + rr;
        const float mu  = s[rr] * (1.f / 768.f);
        const float var = s2[rr] * (1.f / 768.f) - mu * mu;
        const float rs  = rsqrtf(var + 1e-5f);
        char* abase = (char*)Alds + r * 1536;
        const int swz = (r & 7) << 4;
#pragma unroll
        for (int m = 0; m < 3; ++m) {
            const float4 v = vs[rr][m];
            us4 o;
            o.x = f2bf((v.x - mu) * rs * g_[m].x + be_[m].x);
            o.y = f2bf((v.y - mu) * rs * g_[m].y + be_[m].y);
            o.z = f2bf((v.z - mu) * rs * g_[m].z + be_[m].z);
            o.w = f2bf((v.w - mu) * rs * g_[m].w + be_[m].w);
            *(us4*)(abase + (((m << 9) + (l << 3)) ^ swz)) = o;
        }
    }
    __syncthreads();

    // packed store: LDS fragment-transpose -> fully contiguous 16B global stores
    const size_t pb = (size_t)T * 1536;     // short8 units
#pragma unroll
    for (int it = 0; it < 6; ++it) {
        const int idx = it * 256 + tid;     // 0..1535 = ks*64 + lp
        const int lp  = idx & 63;
        const int row = lp & 15;
        const int off = (((idx >> 6) << 5) + ((lp >> 4) << 3)) << 1;   // k0 bytes*2
        const short8 v = *(const short8*)((const char*)Alds + row * 1536
                                          + (off ^ ((row & 7) << 4)));
        *(short8*)((char*)packed + (pb + idx) * 16) = v;
    }
}

// ---------------- K2: GEMM [65536,768]x[768,192], no LDS, no barriers ----------------
__global__ __launch_bounds__(256) void gemm_kernel(
    const unsigned short* __restrict__ packed, const unsigned short* __restrict__ Wb,
    float* __restrict__ out)
{
    const int tid = threadIdx.x, l = tid & 63, cg = tid >> 6;
    const int G = blockIdx.x;                    // 64-row group (4 tiles)
    const short8* A  = (const short8*)packed;
    const short8* Wv = (const short8*)Wb;
    const int bbase = cg * 192 + l;              // (cg*3 + f)*64 + l, f via +64
    const size_t abase = (size_t)G * 6144 + l;   // 4 tiles * 24 * 64

    f32x4 acc[4][3] = {};
#pragma unroll 2
    for (int ks = 0; ks < 24; ++ks) {
        const short8 b0 = Wv[ks * 768 + bbase];
        const short8 b1 = Wv[ks * 768 + bbase + 64];
        const short8 b2 = Wv[ks * 768 + bbase + 128];
#pragma unroll
        for (int t = 0; t < 4; ++t) {
            const short8 a = A[abase + t * 1536 + ks * 64];
            acc[t][0] = __builtin_amdgcn_mfma_f32_16x16x32_bf16(a, b0, acc[t][0], 0, 0, 0);
            acc[t][1] = __builtin_amdgcn_mfma_f32_16x16x32_bf16(a, b1, acc[t][1], 0, 0, 0);
            acc[t][2] = __builtin_amdgcn_mfma_f32_16x16x32_bf16(a, b2, acc[t][2], 0, 0, 0);
        }
    }
    // C/D: col = lane&15, row = (l>>4)*4 + j
    const int colb = cg * 48 + (l & 15);
#pragma unroll
    for (int t = 0; t < 4; ++t) {
        const int r0 = (G << 6) + (t << 4) + ((l >> 4) << 2);
#pragma unroll
        for (int f = 0; f < 3; ++f)
#pragma unroll
            for (int j = 0; j < 4; ++j)
                out[(size_t)(r0 + j) * NOUT + colb + f * 16] = acc[t][f][j];
    }
}

// ---------------- Fallback (round-1 fused, used only if ws too small) ----------------
__global__ __launch_bounds__(256) void fused_fallback(
    const float* __restrict__ x, const float* __restrict__ mask,
    const float* __restrict__ gamma, const float* __restrict__ beta,
    const unsigned short* __restrict__ Wb, float* __restrict__ out)
{
    __shared__ unsigned short Alds[32 * 768];
    const int tid = threadIdx.x, l = tid & 63, wv = tid >> 6;
    const int rowbase = blockIdx.x * 32;
    for (int i = 0; i < 8; ++i) {
        const int r  = (wv << 3) + i;
        const int rg = rowbase + r;
        const int w2 = rg & 31, h2 = (rg >> 5) & 31, d2 = (rg >> 10) & 31, b = rg >> 15;
        const int vbase = ((b * 64 + d2 * 2) * 64 + h2 * 2) * 64 + w2 * 2;
        float vs[12]; float s = 0.f, s2 = 0.f;
#pragma unroll
        for (int m = 0; m < 3; ++m) {
            const int c8 = (m << 8) + (l << 2);
            const int bi = c8 / 96, ch = c8 - bi * 96;
            const int voff = vbase + ((bi >> 2) * 64 + ((bi >> 1) & 1)) * 64 + (bi & 1);
            const float4 v = *(const float4*)(x + (size_t)voff * 96 + ch);
            const float mv = mask[voff];
            vs[m*4+0]=v.x*mv; vs[m*4+1]=v.y*mv; vs[m*4+2]=v.z*mv; vs[m*4+3]=v.w*mv;
            s += (vs[m*4]+vs[m*4+1])+(vs[m*4+2]+vs[m*4+3]);
            s2 += (vs[m*4]*vs[m*4]+vs[m*4+1]*vs[m*4+1])+(vs[m*4+2]*vs[m*4+2]+vs[m*4+3]*vs[m*4+3]);
        }
#pragma unroll
        for (int off = 32; off >= 1; off >>= 1) { s += __shfl_xor(s, off); s2 += __shfl_xor(s2, off); }
        const float mu = s * (1.f/768.f), var = s2 * (1.f/768.f) - mu*mu, rs = rsqrtf(var + 1e-5f);
        const int swz = (r & 7) << 4;
        char* rowp = (char*)Alds + r * 1536;
#pragma unroll
        for (int m = 0; m < 3; ++m) {
            const int c8 = (m << 8) + (l << 2);
            const float4 g = *(const float4*)(gamma + c8), bt = *(const float4*)(beta + c8);
            us4 o;
            o.x = f2bf((vs[m*4+0]-mu)*rs*g.x+bt.x); o.y = f2bf((vs[m*4+1]-mu)*rs*g.y+bt.y);
            o.z = f2bf((vs[m*4+2]-mu)*rs*g.z+bt.z); o.w = f2bf((vs[m*4+3]-mu)*rs*g.w+bt.w);
            *(us4*)(rowp + ((c8 << 1) ^ swz)) = o;
        }
        if (l == 0) {
            float ms = 0.f;
#pragma unroll
            for (int bi = 0; bi < 8; ++bi)
                ms += mask[vbase + ((bi >> 2) * 64 + ((bi >> 1) & 1)) * 64 + (bi & 1)];
            out[OUT0 + rg] = (ms > 0.f) ? 1.0f : 0.0f;
        }
    }
    __syncthreads();
    f32x4 acc[2][3] = {};
    const int lrow = l & 15, kq = (l >> 4) << 4, swz2 = (l & 7) << 4;
    const char* aBase = (const char*)Alds + lrow * 1536;
    const short8* Wv = (const short8*)Wb;
    const int bbase = wv * 192 + l;
#pragma unroll 2
    for (int ks = 0; ks < 24; ++ks) {
        const int ko = ((ks << 6) + kq) ^ swz2;
        short8 a0 = *(const short8*)(aBase + ko);
        short8 a1 = *(const short8*)(aBase + 16 * 1536 + ko);
        short8 b0 = Wv[ks*768+bbase], b1 = Wv[ks*768+bbase+64], b2 = Wv[ks*768+bbase+128];
        acc[0][0] = __builtin_amdgcn_mfma_f32_16x16x32_bf16(a0,b0,acc[0][0],0,0,0);
        acc[1][0] = __builtin_amdgcn_mfma_f32_16x16x32_bf16(a1,b0,acc[1][0],0,0,0);
        acc[0][1] = __builtin_amdgcn_mfma_f32_16x16x32_bf16(a0,b1,acc[0][1],0,0,0);
        acc[1][1] = __builtin_amdgcn_mfma_f32_16x16x32_bf16(a1,b1,acc[1][1],0,0,0);
        acc[0][2] = __builtin_amdgcn_mfma_f32_16x16x32_bf16(a0,b2,acc[0][2],0,0,0);
        acc[1][2] = __builtin_amdgcn_mfma_f32_16x16x32_bf16(a1,b2,acc[1][2],0,0,0);
    }
    const int colb = wv * 48 + lrow;
    const int r0 = rowbase + ((l >> 4) << 2);
#pragma unroll
    for (int fm = 0; fm < 2; ++fm)
#pragma unroll
        for (int fn = 0; fn < 3; ++fn)
#pragma unroll
            for (int j = 0; j < 4; ++j)
                out[(size_t)(r0 + fm*16 + j) * NOUT + colb + fn*16] = acc[fm][fn][j];
}

extern "C" void kernel_launch(void* const* d_in, const int* in_sizes, int n_in,
                              void* d_out, int out_size, void* d_ws, size_t ws_size,
                              hipStream_t stream) {
    const float* x     = (const float*)d_in[0];
    const float* mask  = (const float*)d_in[1];
    const float* gamma = (const float*)d_in[2];
    const float* beta  = (const float*)d_in[3];
    const float* Wm    = (const float*)d_in[4];
    float* out = (float*)d_out;

    const size_t PACKED_BYTES = (size_t)4096 * 24576;   // 100,663,296 B
    const size_t WB_BYTES     = 294912;

    if (ws_size >= PACKED_BYTES + WB_BYTES) {
        unsigned short* packed = (unsigned short*)d_ws;
        unsigned short* Wb     = (unsigned short*)((char*)d_ws + PACKED_BYTES);
        prepw_kernel  <<<576,  256, 0, stream>>>(Wm, Wb);
        ln_pack_kernel<<<4096, 256, 0, stream>>>(x, mask, gamma, beta, packed, out);
        gemm_kernel   <<<1024, 256, 0, stream>>>(packed, Wb, out);
    } else {
        unsigned short* Wb = (unsigned short*)d_ws;
        prepw_kernel  <<<576,  256, 0, stream>>>(Wm, Wb);
        fused_fallback<<<2048, 256, 0, stream>>>(x, mask, gamma, beta, Wb, out);
    }
}